// Round 1
// baseline (422.899 us; speedup 1.0000x reference)
//
#include <hip/hip_runtime.h>
#include <hip/hip_bf16.h>

#define BATCH 128
#define LQ    512
#define LK    512
#define DH    64
#define TQ    16
#define KC    128

// LDS strides (in elements). All chosen 16B-aligned per row, and so that the
// MFMA-fragment ds_read_b128 patterns land at worst 2-way bank conflicts
// (2-way is free on gfx950 -- m136).
#define KSTR  72    // K chunk row: 64 bf16 + 8 pad  (144 B)
#define VSTR  136   // Vt row: 128 bf16 + 8 pad      (272 B)
#define SSTR  516   // score row: 512 fp32 + 4 pad   (2064 B)
#define ASTR  520   // attn row: 512 bf16 + 8 pad    (1040 B)

typedef float  float4v __attribute__((ext_vector_type(4)));
typedef short  short8v __attribute__((ext_vector_type(8)));
typedef short  short4v __attribute__((ext_vector_type(4)));
typedef int    int4v   __attribute__((ext_vector_type(4)));

__device__ __forceinline__ short bf16r(float f) {
  // round-to-nearest-even fp32 -> bf16
  union { float f; unsigned u; } x; x.f = f;
  unsigned r = x.u + 0x7FFFu + ((x.u >> 16) & 1u);
  return (short)(r >> 16);
}

__global__ __launch_bounds__(256)
void sdpa_kernel(const float* __restrict__ Q, const float* __restrict__ K,
                 const float* __restrict__ V, const int* __restrict__ KM,
                 const int* __restrict__ QM, float* __restrict__ OUT,
                 float* __restrict__ ATT)
{
  __shared__ short kvs[KC * KSTR];   // K chunk (bf16) then reused as Vt (bf16)
  __shared__ float sc[TQ * SSTR];    // fp32 scores, full 16x512 row block
  __shared__ short at[TQ * ASTR];    // post-softmax attn (bf16, A-frag layout)

  const int b    = blockIdx.x >> 5;          // 32 q-tiles per batch
  const int q0   = (blockIdx.x & 31) * TQ;
  const int tid  = threadIdx.x;
  const int lane = tid & 63;
  const int wave = tid >> 6;
  const int lm   = lane & 15;                // MFMA m (or n) index
  const int quad = lane >> 4;

  // ---------------- Q A-fragments in registers -------------------------
  // A[m=lane&15][k = quad*8 + j]  (verified layout, m120)
  const float* qrow = Q + ((size_t)(b * LQ + q0 + lm)) * DH + quad * 8;
  short8v aq0, aq1;
  {
    float4v f0 = *(const float4v*)(qrow + 0);
    float4v f1 = *(const float4v*)(qrow + 4);
    float4v f2 = *(const float4v*)(qrow + 32);
    float4v f3 = *(const float4v*)(qrow + 36);
#pragma unroll
    for (int e = 0; e < 4; ++e) {
      aq0[e]     = bf16r(f0[e]);
      aq0[e + 4] = bf16r(f1[e]);
      aq1[e]     = bf16r(f2[e]);
      aq1[e + 4] = bf16r(f3[e]);
    }
  }

  // ---------------- Phase 1: S = Q K^T ---------------------------------
  for (int kt = 0; kt < LK / KC; ++kt) {
    const float* ksrc = K + ((size_t)(b * LK + kt * KC)) * DH;
#pragma unroll
    for (int i = 0; i < 8; ++i) {
      int fl = (tid + i * 256) << 2;       // flat float index in 128x64 tile
      int r  = fl >> 6, c = fl & 63;
      float4v d4 = *(const float4v*)(ksrc + fl);
      short4v s4;
      s4[0] = bf16r(d4[0]); s4[1] = bf16r(d4[1]);
      s4[2] = bf16r(d4[2]); s4[3] = bf16r(d4[3]);
      *(short4v*)&kvs[r * KSTR + c] = s4;
    }
    __syncthreads();
#pragma unroll
    for (int t = 0; t < 2; ++t) {
      int ntl = (wave * 2 + t) * 16;       // local key-tile base in chunk
      const short* bp = &kvs[(ntl + lm) * KSTR + quad * 8];
      short8v b0 = *(const short8v*)(bp);        // d = quad*8+j
      short8v b1 = *(const short8v*)(bp + 32);   // d = 32+quad*8+j
      float4v acc = {0.f, 0.f, 0.f, 0.f};
      acc = __builtin_amdgcn_mfma_f32_16x16x32_bf16(aq0, b0, acc, 0, 0, 0);
      acc = __builtin_amdgcn_mfma_f32_16x16x32_bf16(aq1, b1, acc, 0, 0, 0);
      // C/D layout: col(n)=lane&15, row(m)=quad*4+reg  (verified, m89/m91)
      int n  = kt * KC + ntl + lm;
      int m0 = quad * 4;
      sc[(m0 + 0) * SSTR + n] = acc[0];
      sc[(m0 + 1) * SSTR + n] = acc[1];
      sc[(m0 + 2) * SSTR + n] = acc[2];
      sc[(m0 + 3) * SSTR + n] = acc[3];
    }
    __syncthreads();
  }

  // ---------------- Phase 2: masks + softmax ----------------------------
  // 16 threads per query row (consecutive lanes -> shuffle-reducible)
  const int row = tid >> 4;
  const int col = tid & 15;
  const size_t gro = (size_t)(b * LQ + q0 + row) * LK;
  const int* kmr = KM + gro;
  const int* qmr = QM + gro;
  float s[32];
  float mx = -INFINITY;
#pragma unroll
  for (int j = 0; j < 8; ++j) {
    int kk = col * 4 + j * 64;
    int4v  msk = *(const int4v*)(kmr + kk);
    float4v s4 = *(const float4v*)&sc[row * SSTR + kk];
#pragma unroll
    for (int e = 0; e < 4; ++e) {
      float val = msk[e] ? -INFINITY : s4[e];
      s[j * 4 + e] = val;
      mx = fmaxf(mx, val);
    }
  }
#pragma unroll
  for (int off = 8; off; off >>= 1) mx = fmaxf(mx, __shfl_xor(mx, off, 64));
  float sum = 0.f;
#pragma unroll
  for (int j = 0; j < 32; ++j) {
    float p = __expf((s[j] - mx) * 0.125f);   // masked: exp(-inf)=0
    s[j] = p;
    sum += p;
  }
#pragma unroll
  for (int off = 8; off; off >>= 1) sum += __shfl_xor(sum, off, 64);
  const float inv = 1.f / sum;
  float* arow = ATT + gro;
#pragma unroll
  for (int j = 0; j < 8; ++j) {
    int kk = col * 4 + j * 64;
    int4v qmk = *(const int4v*)(qmr + kk);
    float4v a4;
#pragma unroll
    for (int e = 0; e < 4; ++e)
      a4[e] = qmk[e] ? 0.f : s[j * 4 + e] * inv;
    *(float4v*)(arow + kk) = a4;              // attn output (fp32, coalesced)
    short4v ab;
    ab[0] = bf16r(a4[0]); ab[1] = bf16r(a4[1]);
    ab[2] = bf16r(a4[2]); ab[3] = bf16r(a4[3]);
    *(short4v*)&at[row * ASTR + kk] = ab;     // bf16 copy for PV
  }

  // ---------------- Phase 3: O = A V ------------------------------------
  float4v oacc = {0.f, 0.f, 0.f, 0.f};
  for (int kt = 0; kt < LK / KC; ++kt) {
    const float* vsrc = V + ((size_t)(b * LK + kt * KC)) * DH;
#pragma unroll
    for (int i = 0; i < 8; ++i) {
      int fl = (tid + i * 256) << 2;
      int r = fl >> 6, c = fl & 63;
      float4v d4 = *(const float4v*)(vsrc + fl);
      // transpose on store: Vt[d][k] so B-frags read contiguous along k
      kvs[(c + 0) * VSTR + r] = bf16r(d4[0]);
      kvs[(c + 1) * VSTR + r] = bf16r(d4[1]);
      kvs[(c + 2) * VSTR + r] = bf16r(d4[2]);
      kvs[(c + 3) * VSTR + r] = bf16r(d4[3]);
    }
    __syncthreads();   // also orders Phase-2 `at` writes before reads below
#pragma unroll
    for (int ks = 0; ks < 4; ++ks) {
      const short* ap = &at[lm * ASTR + kt * KC + ks * 32 + quad * 8];
      short8v a8 = *(const short8v*)ap;
      const short* bp = &kvs[(wave * 16 + lm) * VSTR + ks * 32 + quad * 8];
      short8v b8 = *(const short8v*)bp;
      oacc = __builtin_amdgcn_mfma_f32_16x16x32_bf16(a8, b8, oacc, 0, 0, 0);
    }
    __syncthreads();
  }
  {
    int m0 = quad * 4;
    float* obase = OUT + ((size_t)(b * LQ + q0 + m0)) * DH + wave * 16 + lm;
    obase[0 * DH] = oacc[0];
    obase[1 * DH] = oacc[1];
    obase[2 * DH] = oacc[2];
    obase[3 * DH] = oacc[3];
  }
}

extern "C" void kernel_launch(void* const* d_in, const int* in_sizes, int n_in,
                              void* d_out, int out_size, void* d_ws, size_t ws_size,
                              hipStream_t stream) {
  const float* q  = (const float*)d_in[0];
  const float* k  = (const float*)d_in[1];
  const float* v  = (const float*)d_in[2];
  const int*   km = (const int*)d_in[3];
  const int*   qm = (const int*)d_in[4];
  float* out  = (float*)d_out;
  float* attn = out + (size_t)BATCH * LQ * DH;   // outputs concatenated flat
  dim3 grid(BATCH * (LQ / TQ));                  // 4096 blocks
  dim3 block(256);
  hipLaunchKernelGGL(sdpa_kernel, grid, block, 0, stream,
                     q, k, v, km, qm, out, attn);
}

// Round 2
// 378.524 us; speedup vs baseline: 1.1172x; 1.1172x over previous
//
#include <hip/hip_runtime.h>
#include <hip/hip_bf16.h>

#define BATCH 128
#define LQ    512
#define LK    512
#define DH    64
#define TQ    16
#define KC    128

// LDS strides (16-bit elements) -- bank-conflict-verified:
//  KSTR=72 : K rows; b64 stores & b128 frag reads both bank-minimal
//  VROW=136: Vt rows; 32 XOR-swizzled 4-short groups + pad
//  SSTR=520: fp16 scores / bf16 attn overlay; b64 r/w 4-lanes/pair (minimal),
//            b128 phase-3 reads uniform over 8 bank-groups (minimal)
#define KSTR  72
#define VROW  136
#define SSTR  520

typedef float    float4v __attribute__((ext_vector_type(4)));
typedef short    short8v __attribute__((ext_vector_type(8)));
typedef short    short4v __attribute__((ext_vector_type(4)));
typedef int      int4v   __attribute__((ext_vector_type(4)));
typedef _Float16 half4v  __attribute__((ext_vector_type(4)));

__device__ __forceinline__ short bf16r(float f) {
  union { float f; unsigned u; } x; x.f = f;
  unsigned r = x.u + 0x7FFFu + ((x.u >> 16) & 1u);
  return (short)(r >> 16);
}

__global__ __launch_bounds__(256, 4)
void sdpa_kernel(const float* __restrict__ Q, const float* __restrict__ K,
                 const float* __restrict__ V, const int* __restrict__ KM,
                 const int* __restrict__ QM, float* __restrict__ OUT,
                 float* __restrict__ ATT)
{
  __shared__ short kvs[KC * KSTR];   // K chunk (bf16), reused as swizzled Vt
  __shared__ short scs[TQ * SSTR];   // fp16 scores, then bf16 attn (in place)

  const int b    = blockIdx.x >> 5;
  const int q0   = (blockIdx.x & 31) * TQ;
  const int tid  = threadIdx.x;
  const int lane = tid & 63;
  const int wave = tid >> 6;
  const int lm   = lane & 15;
  const int quad = lane >> 4;

  // ----- phase-2 row/col mapping, computed early for mask prefetch --------
  const int row = tid >> 4;
  const int col = tid & 15;
  const size_t gro = (size_t)(b * LQ + q0 + row) * LK;

  // Prefetch key mask NOW: its ~900-cyc HBM latency overlaps all of phase 1.
  int4v kmv[8];
#pragma unroll
  for (int j = 0; j < 8; ++j)
    kmv[j] = *(const int4v*)(KM + gro + col * 4 + j * 64);

  // ---------------- Q A-fragments in registers ---------------------------
  const float* qrow = Q + ((size_t)(b * LQ + q0 + lm)) * DH + quad * 8;
  short8v aq0, aq1;
  {
    float4v f0 = *(const float4v*)(qrow + 0);
    float4v f1 = *(const float4v*)(qrow + 4);
    float4v f2 = *(const float4v*)(qrow + 32);
    float4v f3 = *(const float4v*)(qrow + 36);
#pragma unroll
    for (int e = 0; e < 4; ++e) {
      aq0[e]     = bf16r(f0[e]);
      aq0[e + 4] = bf16r(f1[e]);
      aq1[e]     = bf16r(f2[e]);
      aq1[e + 4] = bf16r(f3[e]);
    }
  }

  // ---------------- Phase 1: S = Q K^T -----------------------------------
  for (int kt = 0; kt < LK / KC; ++kt) {
    const float* ksrc = K + ((size_t)(b * LK + kt * KC)) * DH;
#pragma unroll
    for (int i = 0; i < 8; ++i) {
      int fl = (tid + i * 256) << 2;
      int r  = fl >> 6, c = fl & 63;
      float4v d4 = *(const float4v*)(ksrc + fl);
      short4v s4;
      s4[0] = bf16r(d4[0]); s4[1] = bf16r(d4[1]);
      s4[2] = bf16r(d4[2]); s4[3] = bf16r(d4[3]);
      *(short4v*)&kvs[r * KSTR + c] = s4;
    }
    __syncthreads();
#pragma unroll
    for (int t = 0; t < 2; ++t) {
      int ntl = (wave * 2 + t) * 16;
      const short* bp = &kvs[(ntl + lm) * KSTR + quad * 8];
      short8v b0 = *(const short8v*)(bp);
      short8v b1 = *(const short8v*)(bp + 32);
      float4v acc = {0.f, 0.f, 0.f, 0.f};
      acc = __builtin_amdgcn_mfma_f32_16x16x32_bf16(aq0, b0, acc, 0, 0, 0);
      acc = __builtin_amdgcn_mfma_f32_16x16x32_bf16(aq1, b1, acc, 0, 0, 0);
      int n  = kt * KC + ntl + lm;
      int m0 = quad * 4;
#pragma unroll
      for (int j = 0; j < 4; ++j)
        *(_Float16*)&scs[(m0 + j) * SSTR + n] = (_Float16)acc[j];
    }
    __syncthreads();
  }

  // ---------------- Phase 2: masks + softmax -----------------------------
  float s[32];
  float mx = -INFINITY;
#pragma unroll
  for (int j = 0; j < 8; ++j) {
    half4v h4 = *(const half4v*)&scs[row * SSTR + col * 4 + j * 64];
#pragma unroll
    for (int e = 0; e < 4; ++e) {
      float val = kmv[j][e] ? -INFINITY : (float)h4[e];
      s[j * 4 + e] = val;
      mx = fmaxf(mx, val);
    }
  }
  // issue query-mask loads early: latency overlaps shuffles + exp
  int4v qmv[8];
#pragma unroll
  for (int j = 0; j < 8; ++j)
    qmv[j] = *(const int4v*)(QM + gro + col * 4 + j * 64);
#pragma unroll
  for (int off = 8; off; off >>= 1) mx = fmaxf(mx, __shfl_xor(mx, off, 64));
  float sum = 0.f;
#pragma unroll
  for (int j = 0; j < 32; ++j) {
    float p = __expf((s[j] - mx) * 0.125f);
    s[j] = p;
    sum += p;
  }
#pragma unroll
  for (int off = 8; off; off >>= 1) sum += __shfl_xor(sum, off, 64);
  const float inv = 1.f / sum;
  float* arow = ATT + gro;
#pragma unroll
  for (int j = 0; j < 8; ++j) {
    int kk = col * 4 + j * 64;
    float4v a4;
#pragma unroll
    for (int e = 0; e < 4; ++e)
      a4[e] = qmv[j][e] ? 0.f : s[j * 4 + e] * inv;
    *(float4v*)(arow + kk) = a4;               // fp32 attn out, coalesced
    short4v ab;
    ab[0] = bf16r(a4[0]); ab[1] = bf16r(a4[1]);
    ab[2] = bf16r(a4[2]); ab[3] = bf16r(a4[3]);
    // in-place overlay: exactly the shorts this thread just read
    *(short4v*)&scs[row * SSTR + kk] = ab;
  }

  // ---------------- Phase 3: O = A V -------------------------------------
  float4v oacc = {0.f, 0.f, 0.f, 0.f};
  for (int kt = 0; kt < LK / KC; ++kt) {
    const float* vsrc = V + ((size_t)(b * LK + kt * KC)) * DH;
    // register 4x4 transpose + XOR-swizzled (g ^ (d&31)) b64 stores
#pragma unroll
    for (int it = 0; it < 2; ++it) {
      int Bx = tid + 256 * it;
      int bR = Bx >> 4;          // k0 = 4*bR
      int bC = Bx & 15;          // d0 = 4*bC
      const float* vp = vsrc + bR * 4 * DH + bC * 4;
      float4v r0 = *(const float4v*)(vp);
      float4v r1 = *(const float4v*)(vp + DH);
      float4v r2 = *(const float4v*)(vp + 2 * DH);
      float4v r3 = *(const float4v*)(vp + 3 * DH);
#pragma unroll
      for (int e = 0; e < 4; ++e) {
        int d  = bC * 4 + e;
        int gp = bR ^ (d & 31);
        short4v s4;
        s4[0] = bf16r(r0[e]); s4[1] = bf16r(r1[e]);
        s4[2] = bf16r(r2[e]); s4[3] = bf16r(r3[e]);
        *(short4v*)&kvs[d * VROW + gp * 4] = s4;
      }
    }
    __syncthreads();   // also orders phase-2 attn overlay before A-frag reads
#pragma unroll
    for (int ks = 0; ks < 4; ++ks) {
      const short* ap = &scs[lm * SSTR + kt * KC + ks * 32 + quad * 8];
      short8v a8 = *(const short8v*)ap;
      int n  = wave * 16 + lm;
      int g0 = ks * 8 + quad * 2;
      short4v lo = *(const short4v*)&kvs[n * VROW + ((g0    ) ^ (n & 31)) * 4];
      short4v hi = *(const short4v*)&kvs[n * VROW + ((g0 + 1) ^ (n & 31)) * 4];
      short8v b8;
      b8[0] = lo[0]; b8[1] = lo[1]; b8[2] = lo[2]; b8[3] = lo[3];
      b8[4] = hi[0]; b8[5] = hi[1]; b8[6] = hi[2]; b8[7] = hi[3];
      oacc = __builtin_amdgcn_mfma_f32_16x16x32_bf16(a8, b8, oacc, 0, 0, 0);
    }
    __syncthreads();
  }
  {
    int m0 = quad * 4;
    float* obase = OUT + ((size_t)(b * LQ + q0 + m0)) * DH + wave * 16 + lm;
    obase[0 * DH] = oacc[0];
    obase[1 * DH] = oacc[1];
    obase[2 * DH] = oacc[2];
    obase[3 * DH] = oacc[3];
  }
}

extern "C" void kernel_launch(void* const* d_in, const int* in_sizes, int n_in,
                              void* d_out, int out_size, void* d_ws, size_t ws_size,
                              hipStream_t stream) {
  const float* q  = (const float*)d_in[0];
  const float* k  = (const float*)d_in[1];
  const float* v  = (const float*)d_in[2];
  const int*   km = (const int*)d_in[3];
  const int*   qm = (const int*)d_in[4];
  float* out  = (float*)d_out;
  float* attn = out + (size_t)BATCH * LQ * DH;
  dim3 grid(BATCH * (LQ / TQ));
  dim3 block(256);
  hipLaunchKernelGGL(sdpa_kernel, grid, block, 0, stream,
                     q, k, v, km, qm, out, attn);
}